// Round 2
// baseline (224.566 us; speedup 1.0000x reference)
//
#include <hip/hip_runtime.h>

#define Bdim 16
#define Ndim 1024
#define DINc 128
#define Hh   4
#define Dd   32
#define HDc  128

typedef float  float4v __attribute__((ext_vector_type(4)));
typedef int    int4v   __attribute__((ext_vector_type(4)));
typedef short  short8  __attribute__((ext_vector_type(8)));
typedef unsigned int uint2v __attribute__((ext_vector_type(2)));

__device__ __forceinline__ unsigned short bf16_rne(float f) {
    unsigned u = __float_as_uint(f);
    u = u + 0x7FFFu + ((u >> 16) & 1u);
    return (unsigned short)(u >> 16);
}

// ---------------- proj: h = x@W + b (fp32), emit hT_hi/hT_lo (bf16 split,
// transposed [b][d][n]) + eiT/ejT ([b][h][n]) ----------------
__global__ __launch_bounds__(256, 2) void proj_kernel(
    const float* __restrict__ x, const float* __restrict__ W,
    const float* __restrict__ bias, const float* __restrict__ a,
    unsigned short* __restrict__ hT_hi, unsigned short* __restrict__ hT_lo,
    float* __restrict__ eiT, float* __restrict__ ejT)
{
    __shared__ float sx[32][132];
    const int t = threadIdx.x;
    const int nb = blockIdx.x * 32;          // global row base (16384 rows)
    const int b = nb >> 10;
    const int nloc = nb & 1023;

    // stage x tile: 32 rows x 128 cols, coalesced float4
    #pragma unroll
    for (int r = 0; r < 4; ++r) {
        int idx = r * 256 + t;
        int row = idx >> 5, q = idx & 31;
        *(float4v*)&sx[row][q * 4] =
            *(const float4v*)(x + (size_t)(nb + row) * DINc + q * 4);
    }
    __syncthreads();

    const int ng = t & 7;   const int n0 = ng * 4;   // 4 rows/thread
    const int cg = t >> 3;  const int c0 = cg * 4;   // 4 cols/thread
    const int head = t >> 6;                          // wave = head

    float acc[4][4];
    {
        float4v bv = *(const float4v*)(bias + c0);
        #pragma unroll
        for (int rr = 0; rr < 4; ++rr)
            #pragma unroll
            for (int cc = 0; cc < 4; ++cc) acc[rr][cc] = bv[cc];
    }

    #pragma unroll 4
    for (int k4 = 0; k4 < 32; ++k4) {
        float4v wv[4];
        #pragma unroll
        for (int kk = 0; kk < 4; ++kk)
            wv[kk] = *(const float4v*)(W + (size_t)(k4 * 4 + kk) * HDc + c0);
        #pragma unroll
        for (int rr = 0; rr < 4; ++rr) {
            float4v xv = *(const float4v*)&sx[n0 + rr][k4 * 4]; // broadcast
            #pragma unroll
            for (int kk = 0; kk < 4; ++kk)
                #pragma unroll
                for (int cc = 0; cc < 4; ++cc)
                    acc[rr][cc] = fmaf(xv[kk], wv[kk][cc], acc[rr][cc]);
        }
    }

    // ---- ei/ej: per-row head dot with a_i/a_j, butterfly across cg in head
    const int d0 = c0 & 31;
    float4v ai = *(const float4v*)(a + d0);
    float4v aj = *(const float4v*)(a + Dd + d0);
    float pi[4], pj[4];
    #pragma unroll
    for (int rr = 0; rr < 4; ++rr) {
        pi[rr] = fmaf(acc[rr][3], ai[3], fmaf(acc[rr][2], ai[2],
                 fmaf(acc[rr][1], ai[1], acc[rr][0] * ai[0])));
        pj[rr] = fmaf(acc[rr][3], aj[3], fmaf(acc[rr][2], aj[2],
                 fmaf(acc[rr][1], aj[1], acc[rr][0] * aj[0])));
    }
    #pragma unroll
    for (int off = 8; off <= 32; off <<= 1) {
        #pragma unroll
        for (int rr = 0; rr < 4; ++rr) {
            pi[rr] += __shfl_xor(pi[rr], off);
            pj[rr] += __shfl_xor(pj[rr], off);
        }
    }
    if ((t & 63) < 8) {  // one lane per row-group per wave holds full head sum
        float4v vi = {pi[0], pi[1], pi[2], pi[3]};
        float4v vj = {pj[0], pj[1], pj[2], pj[3]};
        *(float4v*)(eiT + (size_t)(b * Hh + head) * Ndim + nloc + n0) = vi;
        *(float4v*)(ejT + (size_t)(b * Hh + head) * Ndim + nloc + n0) = vj;
    }

    // ---- hT hi/lo bf16-split stores, transposed, coalesced 8B per lane
    #pragma unroll
    for (int cc = 0; cc < 4; ++cc) {
        unsigned int h_[4], l_[4];
        #pragma unroll
        for (int rr = 0; rr < 4; ++rr) {
            float f = acc[rr][cc];
            unsigned short hs = bf16_rne(f);
            float fl = f - __uint_as_float((unsigned)hs << 16);
            h_[rr] = hs;
            l_[rr] = bf16_rne(fl);
        }
        uint2v ph = { h_[0] | (h_[1] << 16), h_[2] | (h_[3] << 16) };
        uint2v pl = { l_[0] | (l_[1] << 16), l_[2] | (l_[3] << 16) };
        size_t off = (size_t)(b * HDc + c0 + cc) * Ndim + nloc + n0;
        *(uint2v*)(hT_hi + off) = ph;
        *(uint2v*)(hT_lo + off) = pl;
    }
}

// ---------------- gat: fused mask+leaky+exp -> bf16 A-frag -> MFMA PV ------
// block = 16 rows x 4 heads (wave = head). No LDS staging, no in-loop barriers.
__global__ __launch_bounds__(256, 4) void gat_kernel(
    const int* __restrict__ adj,
    const unsigned short* __restrict__ hT_hi,
    const unsigned short* __restrict__ hT_lo,
    const float* __restrict__ eiT, const float* __restrict__ ejT,
    float* __restrict__ out)
{
    __shared__ float sden[Hh][16];
    const int t = threadIdx.x;
    const int lane = t & 63;
    const int w = t >> 6;                 // head
    const int b = blockIdx.y;
    const int ibase = blockIdx.x * 16;
    const int i = lane & 15;
    const int quad = lane >> 4;

    const float my_ei = eiT[(size_t)(b * Hh + w) * Ndim + ibase + i];
    const int* adj_p = adj + ((size_t)(b * Ndim + ibase + i)) * Ndim + quad * 8;
    const float* ej_p = ejT + (size_t)(b * Hh + w) * Ndim + quad * 8;
    // B-frag bases: n = lane&15 (d within 16-wide n-tile), k = quad*8 + elem
    const unsigned short* bh0 =
        hT_hi + ((size_t)(b * HDc + w * Dd + i)) * Ndim + quad * 8;
    const unsigned short* bl0 =
        hT_lo + ((size_t)(b * HDc + w * Dd + i)) * Ndim + quad * 8;
    const size_t ntoff = (size_t)16 * Ndim;   // n-tile 1: d += 16

    float4v C0 = {0.f, 0.f, 0.f, 0.f};
    float4v C1 = {0.f, 0.f, 0.f, 0.f};
    float den = 0.f;

    #pragma unroll 2
    for (int jb = 0; jb < Ndim; jb += 32) {
        int4v  a0 = __builtin_nontemporal_load((const int4v*)(adj_p + jb));
        int4v  a1 = __builtin_nontemporal_load((const int4v*)(adj_p + jb + 4));
        float4v e0 = *(const float4v*)(ej_p + jb);
        float4v e1 = *(const float4v*)(ej_p + jb + 4);
        short8 Bh0 = *(const short8*)(bh0 + jb);
        short8 Bh1 = *(const short8*)(bh0 + ntoff + jb);
        short8 Bl0 = *(const short8*)(bl0 + jb);
        short8 Bl1 = *(const short8*)(bl0 + ntoff + jb);

        short8 A;
        #pragma unroll
        for (int k = 0; k < 8; ++k) {
            int   av = (k < 4) ? a0[k] : a1[k - 4];
            float ev = (k < 4) ? e0[k] : e1[k - 4];
            float e = my_ei + ev;
            e = fmaf(fminf(e, 0.f), 0.2f, fmaxf(e, 0.f));  // leaky 0.2
            float p = (av > 0) ? __expf(e) : 0.f;
            den += p;
            A[k] = (short)bf16_rne(p);
        }

        C0 = __builtin_amdgcn_mfma_f32_16x16x32_bf16(A, Bh0, C0, 0, 0, 0);
        C0 = __builtin_amdgcn_mfma_f32_16x16x32_bf16(A, Bl0, C0, 0, 0, 0);
        C1 = __builtin_amdgcn_mfma_f32_16x16x32_bf16(A, Bh1, C1, 0, 0, 0);
        C1 = __builtin_amdgcn_mfma_f32_16x16x32_bf16(A, Bl1, C1, 0, 0, 0);
    }

    // den: lane holds partial for (i, quad j-range) -> allreduce over quad
    den += __shfl_xor(den, 16);
    den += __shfl_xor(den, 32);
    if (quad == 0) sden[w][i] = den;
    __syncthreads();

    // C/D layout: col = lane&15, row = quad*4 + reg
    float* outp = out + ((size_t)(b * Ndim + ibase)) * HDc + w * Dd + i;
    #pragma unroll
    for (int reg = 0; reg < 4; ++reg) {
        int row = quad * 4 + reg;
        float r = 1.0f / sden[w][row];
        outp[(size_t)row * HDc]      = C0[reg] * r;
        outp[(size_t)row * HDc + 16] = C1[reg] * r;
    }
}

extern "C" void kernel_launch(void* const* d_in, const int* in_sizes, int n_in,
                              void* d_out, int out_size, void* d_ws, size_t ws_size,
                              hipStream_t stream) {
    const float* x    = (const float*)d_in[0];
    const int*   adj  = (const int*)d_in[1];
    const float* W    = (const float*)d_in[2];
    const float* bias = (const float*)d_in[3];
    const float* a    = (const float*)d_in[4];
    float* out = (float*)d_out;

    // workspace: hT_hi 4MB | hT_lo 4MB | eiT 256KB | ejT 256KB  (= 8.9 MB)
    unsigned short* hT_hi = (unsigned short*)d_ws;
    unsigned short* hT_lo = hT_hi + (size_t)Bdim * HDc * Ndim;
    float* eiT = (float*)(hT_lo + (size_t)Bdim * HDc * Ndim);
    float* ejT = eiT + (size_t)Bdim * Hh * Ndim;

    proj_kernel<<<dim3((Bdim * Ndim) / 32), dim3(256), 0, stream>>>(
        x, W, bias, a, hT_hi, hT_lo, eiT, ejT);

    gat_kernel<<<dim3(Ndim / 16, Bdim), dim3(256), 0, stream>>>(
        adj, hT_hi, hT_lo, eiT, ejT, out);
}

// Round 3
// 219.172 us; speedup vs baseline: 1.0246x; 1.0246x over previous
//
#include <hip/hip_runtime.h>
#include <hip/hip_bf16.h>

#define Bdim 16
#define Ndim 1024
#define DINc 128
#define Hh   4
#define Dd   32
#define HDc  128
#define L2E  1.4426950408889634f

typedef float  float4v  __attribute__((ext_vector_type(4)));
typedef int    int4v    __attribute__((ext_vector_type(4)));
typedef short  short8   __attribute__((ext_vector_type(8)));
typedef unsigned short ushort4v __attribute__((ext_vector_type(4)));

__device__ __forceinline__ unsigned short bf16_rne(float f) {
    unsigned u = __float_as_uint(f);
    u = u + 0x7FFFu + ((u >> 16) & 1u);
    return (unsigned short)(u >> 16);
}

// ---------- split_w: WT_hi/lo[144][128] in B-frag layout + bias2[144] ----------
// rows 0..127: W^T bf16 hi/lo; rows 128..131: (W @ a_i per head)^T * log2e;
// rows 132..135: same for a_j; rows 136..143: zero pad. bias2 likewise.
__global__ void split_w_kernel(const float* __restrict__ W,
                               const float* __restrict__ bias,
                               const float* __restrict__ a,
                               unsigned short* __restrict__ WTh,
                               unsigned short* __restrict__ WTl,
                               float* __restrict__ bias2)
{
    const int t = threadIdx.x, blk = blockIdx.x;
    if (blk < 16) {
        int r  = blk * 8 + (t >> 5);
        int k0 = (t & 31) * 4;
        #pragma unroll
        for (int j = 0; j < 4; ++j) {
            float f = W[(size_t)(k0 + j) * HDc + r];
            unsigned short hi = bf16_rne(f);
            float fl = f - __uint_as_float((unsigned)hi << 16);
            WTh[r * 128 + k0 + j] = hi;
            WTl[r * 128 + k0 + j] = bf16_rne(fl);
        }
    } else {
        if (t < 128) {
            float si[4] = {0,0,0,0}, sj[4] = {0,0,0,0};
            for (int hh = 0; hh < 4; ++hh)
                for (int d = 0; d < 32; ++d) {
                    float w = W[(size_t)t * HDc + hh * 32 + d];
                    si[hh] = fmaf(w, a[d],      si[hh]);
                    sj[hh] = fmaf(w, a[Dd + d], sj[hh]);
                }
            #pragma unroll
            for (int hh = 0; hh < 4; ++hh) {
                float vi = si[hh] * L2E, vj = sj[hh] * L2E;
                unsigned short hi = bf16_rne(vi);
                WTh[(128 + hh) * 128 + t] = hi;
                WTl[(128 + hh) * 128 + t] =
                    bf16_rne(vi - __uint_as_float((unsigned)hi << 16));
                unsigned short hj = bf16_rne(vj);
                WTh[(132 + hh) * 128 + t] = hj;
                WTl[(132 + hh) * 128 + t] =
                    bf16_rne(vj - __uint_as_float((unsigned)hj << 16));
            }
            bias2[t] = bias[t];
        } else {
            int z = t - 128;
            for (int r = 136; r < 144; ++r) { WTh[r * 128 + z] = 0; WTl[r * 128 + z] = 0; }
            if (z < 8) {
                const float* av = (z < 4) ? a : a + Dd;
                int hh = z & 3;
                float s = 0.f;
                for (int d = 0; d < 32; ++d) s = fmaf(bias[hh * 32 + d], av[d], s);
                bias2[128 + z] = s * L2E;
            } else if (z < 16) {
                bias2[128 + z] = 0.f;
            }
        }
    }
}

// ---------- proj: [h | ei | ej] = x @ [W | wa_i | wa_j] via bf16-split MFMA ----------
__global__ __launch_bounds__(256, 2) void proj_kernel(
    const float* __restrict__ x,
    const unsigned short* __restrict__ WTh, const unsigned short* __restrict__ WTl,
    const float* __restrict__ bias2,
    unsigned short* __restrict__ hTh, unsigned short* __restrict__ hTl,
    float* __restrict__ eiT, float* __restrict__ ejT)
{
    const int t = threadIdx.x;
    const int w = t >> 6, lane = t & 63, l16 = lane & 15, q = lane >> 4;
    const int nb = blockIdx.x * 64;
    const int b = nb >> 10;
    const int nloc0 = (nb & 1023) + w * 16;

    const float* xp = x + (size_t)(nb + w * 16 + l16) * DINc + q * 8;
    float4v C[9];
    #pragma unroll
    for (int nt = 0; nt < 9; ++nt) C[nt] = (float4v){0.f, 0.f, 0.f, 0.f};

    #pragma unroll
    for (int ks = 0; ks < 4; ++ks) {
        float4v x0 = *(const float4v*)(xp + ks * 32);
        float4v x1 = *(const float4v*)(xp + ks * 32 + 4);
        short8 Ah, Al;
        #pragma unroll
        for (int e = 0; e < 8; ++e) {
            float f = (e < 4) ? x0[e] : x1[e - 4];
            unsigned short hi = bf16_rne(f);
            Ah[e] = (short)hi;
            Al[e] = (short)bf16_rne(f - __uint_as_float((unsigned)hi << 16));
        }
        #pragma unroll
        for (int nt = 0; nt < 9; ++nt) {
            size_t wo = (size_t)(nt * 16 + l16) * 128 + ks * 32 + q * 8;
            short8 Bh = *(const short8*)(WTh + wo);
            short8 Bl = *(const short8*)(WTl + wo);
            C[nt] = __builtin_amdgcn_mfma_f32_16x16x32_bf16(Ah, Bh, C[nt], 0, 0, 0);
            C[nt] = __builtin_amdgcn_mfma_f32_16x16x32_bf16(Ah, Bl, C[nt], 0, 0, 0);
            C[nt] = __builtin_amdgcn_mfma_f32_16x16x32_bf16(Al, Bh, C[nt], 0, 0, 0);
        }
    }

    const int nodeloc = nloc0 + q * 4;
    #pragma unroll
    for (int nt = 0; nt < 8; ++nt) {
        int col = nt * 16 + l16;
        float bv = bias2[col];
        ushort4v h4, l4;
        #pragma unroll
        for (int r = 0; r < 4; ++r) {
            float f = C[nt][r] + bv;
            unsigned short hs = bf16_rne(f);
            h4[r] = hs;
            l4[r] = bf16_rne(f - __uint_as_float((unsigned)hs << 16));
        }
        size_t off = (size_t)(b * HDc + col) * Ndim + nodeloc;
        *(ushort4v*)(hTh + off) = h4;
        *(ushort4v*)(hTl + off) = l4;
    }
    {
        float bv = bias2[128 + l16];
        float4v v = {C[8][0] + bv, C[8][1] + bv, C[8][2] + bv, C[8][3] + bv};
        if (l16 < 4)
            *(float4v*)(eiT + (size_t)(b * Hh + l16) * Ndim + nodeloc) = v;
        else if (l16 < 8)
            *(float4v*)(ejT + (size_t)(b * Hh + (l16 - 4)) * Ndim + nodeloc) = v;
    }
}

// ---------- gat: register-pipelined score->MFMA PV, no barriers in loop ----------
__global__ __launch_bounds__(256, 4) void gat_kernel(
    const int* __restrict__ adj,
    const unsigned short* __restrict__ hTh, const unsigned short* __restrict__ hTl,
    const float* __restrict__ eiT, const float* __restrict__ ejT,
    float* __restrict__ out)
{
    __shared__ float sden[Hh][16];
    const int t = threadIdx.x, lane = t & 63, w = t >> 6;
    const int L = blockIdx.x;
    const int kk = L >> 3;
    const int b = (L & 7) + 8 * (kk & 1);   // batch->XCD pinning
    const int ibase = (kk >> 1) * 16;
    const int i = lane & 15, q = lane >> 4;

    const float my_ei = eiT[(size_t)(b * Hh + w) * Ndim + ibase + i];
    const int* adj_p = adj + ((size_t)(b * Ndim + ibase + i)) * Ndim + q * 8;
    const float* ej_p = ejT + (size_t)(b * Hh + w) * Ndim + q * 8;
    const unsigned short* bh0 = hTh + ((size_t)(b * HDc + w * Dd + i)) * Ndim + q * 8;
    const unsigned short* bl0 = hTl + ((size_t)(b * HDc + w * Dd + i)) * Ndim + q * 8;
    const size_t ntoff = (size_t)16 * Ndim;

    float4v C0 = {0.f, 0.f, 0.f, 0.f};
    float4v C1 = {0.f, 0.f, 0.f, 0.f};
    float den = 0.f;

    int4v   Aj[4][2];
    float4v Ej[2][2];
    short8  Bh[2][2], Bl[2][2];

#define LOAD_ADJ(buf, T) { int o_ = ((T) < 31 ? (T) : 31) * 32;                      \
    Aj[buf][0] = __builtin_nontemporal_load((const int4v*)(adj_p + o_));             \
    Aj[buf][1] = __builtin_nontemporal_load((const int4v*)(adj_p + o_ + 4)); }
#define LOAD_HT(buf, T) { int o_ = ((T) < 31 ? (T) : 31) * 32;                       \
    Ej[buf][0] = *(const float4v*)(ej_p + o_);                                       \
    Ej[buf][1] = *(const float4v*)(ej_p + o_ + 4);                                   \
    Bh[buf][0] = *(const short8*)(bh0 + o_);                                         \
    Bh[buf][1] = *(const short8*)(bh0 + ntoff + o_);                                 \
    Bl[buf][0] = *(const short8*)(bl0 + o_);                                         \
    Bl[buf][1] = *(const short8*)(bl0 + ntoff + o_); }

    LOAD_ADJ(0, 0); LOAD_ADJ(1, 1); LOAD_ADJ(2, 2);
    LOAD_HT(0, 0);

    for (int o = 0; o < 8; ++o) {
        #pragma unroll
        for (int u = 0; u < 4; ++u) {
            const int it = 4 * o + u;
            LOAD_ADJ((u + 3) & 3, it + 3);
            LOAD_HT((u + 1) & 1, it + 1);
            const int4v  a0 = Aj[u & 3][0], a1 = Aj[u & 3][1];
            const float4v e0 = Ej[u & 1][0], e1 = Ej[u & 1][1];
            float p[8];
            #pragma unroll
            for (int k = 0; k < 8; ++k) {
                int   av = (k < 4) ? a0[k] : a1[k - 4];
                float ev = (k < 4) ? e0[k] : e1[k - 4];
                float e = my_ei + ev;
                float s = e > 0.f ? e : 0.2f * e;
                s = av > 0 ? s : -1e38f;
                float pe = __builtin_amdgcn_exp2f(s);
                den += pe;
                p[k] = pe;
            }
            union { __hip_bfloat162 h2[4]; short8 s8; } A;
            #pragma unroll
            for (int k2 = 0; k2 < 4; ++k2)
                A.h2[k2] = __float22bfloat162_rn(make_float2(p[2 * k2], p[2 * k2 + 1]));
            C0 = __builtin_amdgcn_mfma_f32_16x16x32_bf16(A.s8, Bh[u & 1][0], C0, 0, 0, 0);
            C0 = __builtin_amdgcn_mfma_f32_16x16x32_bf16(A.s8, Bl[u & 1][0], C0, 0, 0, 0);
            C1 = __builtin_amdgcn_mfma_f32_16x16x32_bf16(A.s8, Bh[u & 1][1], C1, 0, 0, 0);
            C1 = __builtin_amdgcn_mfma_f32_16x16x32_bf16(A.s8, Bl[u & 1][1], C1, 0, 0, 0);
        }
    }
#undef LOAD_ADJ
#undef LOAD_HT

    den += __shfl_xor(den, 16);
    den += __shfl_xor(den, 32);
    if (q == 0) sden[w][i] = den;
    __syncthreads();

    float* outp = out + ((size_t)(b * Ndim + ibase)) * HDc + w * Dd + i;
    #pragma unroll
    for (int reg = 0; reg < 4; ++reg) {
        int row = q * 4 + reg;
        float r = 1.0f / sden[w][row];
        outp[(size_t)row * HDc]      = C0[reg] * r;
        outp[(size_t)row * HDc + 16] = C1[reg] * r;
    }
}

extern "C" void kernel_launch(void* const* d_in, const int* in_sizes, int n_in,
                              void* d_out, int out_size, void* d_ws, size_t ws_size,
                              hipStream_t stream) {
    const float* x    = (const float*)d_in[0];
    const int*   adj  = (const int*)d_in[1];
    const float* W    = (const float*)d_in[2];
    const float* bias = (const float*)d_in[3];
    const float* a    = (const float*)d_in[4];
    float* out = (float*)d_out;

    unsigned short* hTh = (unsigned short*)d_ws;
    unsigned short* hTl = hTh + (size_t)Bdim * HDc * Ndim;
    float* eiT = (float*)(hTl + (size_t)Bdim * HDc * Ndim);
    float* ejT = eiT + (size_t)Bdim * Hh * Ndim;
    unsigned short* WTh = (unsigned short*)(ejT + (size_t)Bdim * Hh * Ndim);
    unsigned short* WTl = WTh + 144 * 128;
    float* bias2 = (float*)(WTl + 144 * 128);

    split_w_kernel<<<dim3(17), dim3(256), 0, stream>>>(W, bias, a, WTh, WTl, bias2);
    proj_kernel<<<dim3((Bdim * Ndim) / 64), dim3(256), 0, stream>>>(
        x, WTh, WTl, bias2, hTh, hTl, eiT, ejT);
    gat_kernel<<<dim3((Ndim / 16) * Bdim), dim3(256), 0, stream>>>(
        adj, hTh, hTl, eiT, ejT, out);
}

// Round 4
// 172.929 us; speedup vs baseline: 1.2986x; 1.2674x over previous
//
#include <hip/hip_runtime.h>
#include <hip/hip_bf16.h>

#define Bdim 16
#define Ndim 1024
#define DINc 128
#define Hh   4
#define Dd   32
#define HDc  128
#define L2E  1.4426950408889634f

typedef float  float4v  __attribute__((ext_vector_type(4)));
typedef int    int4v    __attribute__((ext_vector_type(4)));
typedef short  short8   __attribute__((ext_vector_type(8)));
typedef unsigned short ushort4v __attribute__((ext_vector_type(4)));

__device__ __forceinline__ unsigned short bf16_rne(float f) {
    unsigned u = __float_as_uint(f);
    u = u + 0x7FFFu + ((u >> 16) & 1u);
    return (unsigned short)(u >> 16);
}

__device__ __forceinline__ void gl_lds16(const void* g, void* l) {
    __builtin_amdgcn_global_load_lds(
        (const __attribute__((address_space(1))) unsigned int*)g,
        (__attribute__((address_space(3))) unsigned int*)l, 16, 0, 0);
}

// ---------------- pack: adj (64MB) -> bitmask (2MB), perfectly sequential ----
__global__ __launch_bounds__(256) void pack_kernel(
    const int* __restrict__ adj, unsigned long long* __restrict__ pk64)
{
    const int g = (blockIdx.x * 256 + threadIdx.x) >> 6;   // wave 0..8191
    const int lane = threadIdx.x & 63;
    const int* src = adj + (size_t)g * 2048 + lane;        // 8KB contiguous/wave
    #pragma unroll 4
    for (int k = 0; k < 32; ++k) {
        int v = src[k * 64];
        unsigned long long m = __ballot(v > 0);
        if (lane == 0) pk64[(size_t)g * 32 + k] = m;
    }
}

// ---------------- split_w: WT hi/lo [144][128] + bias2[144] -----------------
// rows 0..127: W^T; 128..131: (W@a_i)^T*log2e; 132..135: (W@a_j)^T*log2e; pad 0.
__global__ __launch_bounds__(256) void split_w_kernel(
    const float* __restrict__ W, const float* __restrict__ bias,
    const float* __restrict__ a,
    unsigned short* __restrict__ WTh, unsigned short* __restrict__ WTl,
    float* __restrict__ bias2)
{
    const int t = threadIdx.x, blk = blockIdx.x;
    if (blk < 16) {
        int r  = blk * 8 + (t >> 5);
        int k0 = (t & 31) * 4;
        #pragma unroll
        for (int j = 0; j < 4; ++j) {
            float f = W[(size_t)(k0 + j) * HDc + r];
            unsigned short hi = bf16_rne(f);
            WTh[r * 128 + k0 + j] = hi;
            WTl[r * 128 + k0 + j] = bf16_rne(f - __uint_as_float((unsigned)hi << 16));
        }
    } else {
        #pragma unroll
        for (int rep = 0; rep < 2; ++rep) {
            int task = t + rep * 256;          // (row, hh): 512 tasks
            int row = task >> 2, hh = task & 3;
            float si = 0.f, sj = 0.f;
            #pragma unroll
            for (int d4 = 0; d4 < 8; ++d4) {
                float4v wv = *(const float4v*)(W + (size_t)row * HDc + hh * 32 + d4 * 4);
                float4v av = *(const float4v*)(a + d4 * 4);
                float4v bv = *(const float4v*)(a + Dd + d4 * 4);
                #pragma unroll
                for (int kk = 0; kk < 4; ++kk) {
                    si = fmaf(wv[kk], av[kk], si);
                    sj = fmaf(wv[kk], bv[kk], sj);
                }
            }
            float vi = si * L2E, vj = sj * L2E;
            unsigned short hi = bf16_rne(vi);
            WTh[(128 + hh) * 128 + row] = hi;
            WTl[(128 + hh) * 128 + row] = bf16_rne(vi - __uint_as_float((unsigned)hi << 16));
            unsigned short hj = bf16_rne(vj);
            WTh[(132 + hh) * 128 + row] = hj;
            WTl[(132 + hh) * 128 + row] = bf16_rne(vj - __uint_as_float((unsigned)hj << 16));
        }
        #pragma unroll
        for (int rp = 0; rp < 4; ++rp) {
            int idx = t + rp * 256;            // pad rows 136..143
            WTh[136 * 128 + idx] = 0;
            WTl[136 * 128 + idx] = 0;
        }
        if (t < 128) {
            bias2[t] = bias[t];
        } else if (t < 136) {
            int z = t - 128;
            const float* av = (z < 4) ? a : a + Dd;
            int hh = z & 3;
            float s = 0.f;
            for (int d = 0; d < 32; ++d) s = fmaf(bias[hh * 32 + d], av[d], s);
            bias2[128 + z] = s * L2E;
        } else if (t < 144) {
            bias2[t] = 0.f;
        }
    }
}

// ---------------- proj: [h|ei|ej] = x @ [W|wa_i|wa_j], bf16-split MFMA -------
// wave = one 16-row x tile, staged to LDS via swizzled DMA (contiguous rows).
__global__ __launch_bounds__(256) void proj_kernel(
    const float* __restrict__ x,
    const unsigned short* __restrict__ WTh, const unsigned short* __restrict__ WTl,
    const float* __restrict__ bias2,
    unsigned short* __restrict__ hTh, unsigned short* __restrict__ hTl,
    float* __restrict__ eiT, float* __restrict__ ejT)
{
    __shared__ unsigned char xs[4][8192];
    const int t = threadIdx.x, lane = t & 63, w = t >> 6;
    const int tile = blockIdx.x * 4 + w;           // 0..1023
    const int nb = tile * 16;
    const int b = nb >> 10, nloc = nb & 1023;
    const int l16 = lane & 15, q = lane >> 4;

    {   // stage 16 rows x 512B, row-contiguous global reads, XOR-swizzled LDS
        const char* gx = (const char*)(x + (size_t)nb * DINc);
        char* lx = (char*)xs[w];
        int rsub = lane >> 5;                      // 0..1
        int p = lane & 31;                         // position in row
        #pragma unroll
        for (int c = 0; c < 8; ++c) {
            int ra = c * 2 + rsub;
            int gb = (p & 24) | ((p & 7) ^ (ra & 7));
            gl_lds16(gx + (size_t)ra * 512 + gb * 16, lx + c * 1024);
        }
    }
    asm volatile("s_waitcnt vmcnt(0)" ::: "memory");

    float4v C[9];
    #pragma unroll
    for (int nt = 0; nt < 9; ++nt) C[nt] = (float4v){0.f, 0.f, 0.f, 0.f};

    const int sw = l16 & 7;
    #pragma unroll
    for (int ks = 0; ks < 4; ++ks) {
        int blk0 = ks * 8 + 2 * q;
        int p0 = (blk0 & 24) | ((blk0 & 7) ^ sw);
        int p1 = ((blk0 + 1) & 24) | (((blk0 + 1) & 7) ^ sw);
        float4v x0 = *(const float4v*)(xs[w] + l16 * 512 + p0 * 16);
        float4v x1 = *(const float4v*)(xs[w] + l16 * 512 + p1 * 16);
        short8 Ah, Al;
        #pragma unroll
        for (int e = 0; e < 8; ++e) {
            float f = (e < 4) ? x0[e] : x1[e - 4];
            unsigned short hi = bf16_rne(f);
            Ah[e] = (short)hi;
            Al[e] = (short)bf16_rne(f - __uint_as_float((unsigned)hi << 16));
        }
        #pragma unroll
        for (int nt = 0; nt < 9; ++nt) {
            size_t wo = (size_t)(nt * 16 + l16) * 128 + ks * 32 + q * 8;
            short8 Bh = *(const short8*)(WTh + wo);
            short8 Bl = *(const short8*)(WTl + wo);
            C[nt] = __builtin_amdgcn_mfma_f32_16x16x32_bf16(Ah, Bh, C[nt], 0, 0, 0);
            C[nt] = __builtin_amdgcn_mfma_f32_16x16x32_bf16(Ah, Bl, C[nt], 0, 0, 0);
            C[nt] = __builtin_amdgcn_mfma_f32_16x16x32_bf16(Al, Bh, C[nt], 0, 0, 0);
        }
    }

    const int nodeloc = nloc + q * 4;              // C rows = q*4+reg
    #pragma unroll
    for (int nt = 0; nt < 8; ++nt) {
        int col = nt * 16 + l16;
        float bv = bias2[col];
        ushort4v h4, l4;
        #pragma unroll
        for (int r = 0; r < 4; ++r) {
            float f = C[nt][r] + bv;
            unsigned short hs = bf16_rne(f);
            h4[r] = hs;
            l4[r] = bf16_rne(f - __uint_as_float((unsigned)hs << 16));
        }
        size_t off = (size_t)(b * HDc + col) * Ndim + nodeloc;
        *(ushort4v*)(hTh + off) = h4;
        *(ushort4v*)(hTl + off) = l4;
    }
    {
        float bv = bias2[128 + l16];
        float4v v = {C[8][0] + bv, C[8][1] + bv, C[8][2] + bv, C[8][3] + bv};
        if (l16 < 4)
            *(float4v*)(eiT + (size_t)(b * Hh + l16) * Ndim + nodeloc) = v;
        else if (l16 < 8)
            *(float4v*)(ejT + (size_t)(b * Hh + (l16 - 4)) * Ndim + nodeloc) = v;
    }
}

// ---------------- gat: packed-adj + per-wave DMA ring, no in-loop barriers ---
// block = 64 i-rows x 4 heads (wave = head). LDS: pk 8K | ej 16K | 4x12K rings.
__global__ __launch_bounds__(256) void gat_kernel(
    const unsigned int* __restrict__ pk,
    const unsigned short* __restrict__ hTh, const unsigned short* __restrict__ hTl,
    const float* __restrict__ eiT, const float* __restrict__ ejT,
    float* __restrict__ out)
{
    __shared__ unsigned char smem[73728];
    const int t = threadIdx.x, lane = t & 63, w = t >> 6;
    const int L = blockIdx.x;
    const int b = (L & 7) + 8 * ((L >> 3) & 1);    // batch -> XCD pinning
    const int ibase = (L >> 4) * 64;
    const int i = lane & 15, q = lane >> 4;

    // ---- stage packed adj rows (rotated by +r dwords to kill bank alias)
    {
        int r = t >> 2, dbase = (t & 3) * 8;
        const unsigned int* src = pk + ((size_t)(b * Ndim + ibase + r)) * 32 + dbase;
        int4v v0 = *(const int4v*)(src);
        int4v v1 = *(const int4v*)(src + 4);
        unsigned int* dst = (unsigned int*)smem + r * 32;
        #pragma unroll
        for (int k = 0; k < 4; ++k) dst[(dbase + k + r) & 31] = (unsigned)v0[k];
        #pragma unroll
        for (int k = 0; k < 4; ++k) dst[(dbase + 4 + k + r) & 31] = (unsigned)v1[k];
    }
    // ---- ei preload
    float ei_[4];
    #pragma unroll
    for (int it = 0; it < 4; ++it)
        ei_[it] = eiT[(size_t)(b * Hh + w) * Ndim + ibase + it * 16 + i];

    __syncthreads();   // pk staged (drains all vmem too)

    // ---- ej DMA: wave's head row, 4KB, once
    const char* gej = (const char*)(ejT + ((size_t)b * Hh + w) * Ndim);
    char* lej = (char*)smem + 8192 + w * 4096;
    #pragma unroll
    for (int c = 0; c < 4; ++c)
        gl_lds16(gej + c * 1024 + lane * 16, lej + c * 1024);

    // ---- hT DMA setup: wave rows d = 0..31 (global w*32+d), swizzled blocks
    const char* gh  = (const char*)(hTh + ((size_t)b * HDc + w * Dd) * Ndim);
    const char* glo = (const char*)(hTl + ((size_t)b * HDc + w * Dd) * Ndim);
    const int drel = lane >> 2, m = lane & 3;
    const int s = m ^ ((drel >> 1) & 3);
    const size_t lane_off = (size_t)drel * 2048 + s * 16;
    char* lws = (char*)smem + 24576 + w * 12288;

#define ISSUE(JT, SLOT) {                                              \
    const char* gh_ = gh  + (size_t)(JT) * 64;                         \
    const char* gl_ = glo + (size_t)(JT) * 64;                         \
    char* lb_ = lws + (SLOT) * 4096;                                   \
    gl_lds16(gh_ + lane_off,         lb_);                             \
    gl_lds16(gh_ + 32768 + lane_off, lb_ + 1024);                      \
    gl_lds16(gl_ + lane_off,         lb_ + 2048);                      \
    gl_lds16(gl_ + 32768 + lane_off, lb_ + 3072); }

    ISSUE(0, 0); ISSUE(1, 1);

    float4v C[4][2];
    #pragma unroll
    for (int it = 0; it < 4; ++it) {
        C[it][0] = (float4v){0.f, 0.f, 0.f, 0.f};
        C[it][1] = (float4v){0.f, 0.f, 0.f, 0.f};
    }
    float den[4] = {0.f, 0.f, 0.f, 0.f};
    const unsigned int* pkl = (const unsigned int*)smem;
    const float* ejl = (const float*)(smem + 8192 + w * 4096);
    const int xo = ((q ^ ((i >> 1) & 3)) << 4);

    int slot_c = 0;
    for (int jt = 0; jt < 32; ++jt) {
        int ji = jt + 2; if (ji > 31) ji = 31;
        int slot_i = slot_c + 2; if (slot_i >= 3) slot_i -= 3;
        ISSUE(ji, slot_i);
        asm volatile("s_waitcnt vmcnt(8)" ::: "memory");

        const char* lb = lws + slot_c * 4096;
        short8 Bh0 = *(const short8*)(lb + i * 64 + xo);
        short8 Bh1 = *(const short8*)(lb + 1024 + i * 64 + xo);
        short8 Bl0 = *(const short8*)(lb + 2048 + i * 64 + xo);
        short8 Bl1 = *(const short8*)(lb + 3072 + i * 64 + xo);
        float4v e0 = *(const float4v*)(ejl + jt * 32 + q * 8);
        float4v e1 = *(const float4v*)(ejl + jt * 32 + q * 8 + 4);

        #pragma unroll
        for (int it = 0; it < 4; ++it) {
            int r = it * 16 + i;
            unsigned bits = (pkl[r * 32 + ((jt + r) & 31)] >> (q * 8)) & 0xffu;
            float p[8];
            #pragma unroll
            for (int k = 0; k < 8; ++k) {
                float ev = (k < 4) ? e0[k] : e1[k - 4];
                float e = ei_[it] + ev;              // already * log2e
                float sL = e > 0.f ? e : 0.2f * e;   // leaky (homogeneous)
                float pe = ((bits >> k) & 1u) ? __builtin_amdgcn_exp2f(sL) : 0.f;
                den[it] += pe;
                p[k] = pe;
            }
            union { __hip_bfloat162 h2[4]; short8 s8; } A;
            #pragma unroll
            for (int k2 = 0; k2 < 4; ++k2)
                A.h2[k2] = __float22bfloat162_rn(make_float2(p[2 * k2], p[2 * k2 + 1]));
            C[it][0] = __builtin_amdgcn_mfma_f32_16x16x32_bf16(A.s8, Bh0, C[it][0], 0, 0, 0);
            C[it][0] = __builtin_amdgcn_mfma_f32_16x16x32_bf16(A.s8, Bl0, C[it][0], 0, 0, 0);
            C[it][1] = __builtin_amdgcn_mfma_f32_16x16x32_bf16(A.s8, Bh1, C[it][1], 0, 0, 0);
            C[it][1] = __builtin_amdgcn_mfma_f32_16x16x32_bf16(A.s8, Bl1, C[it][1], 0, 0, 0);
        }
        slot_c = (slot_c == 2) ? 0 : slot_c + 1;
    }
#undef ISSUE

    #pragma unroll
    for (int it = 0; it < 4; ++it) {
        float d_ = den[it];
        d_ += __shfl_xor(d_, 16);
        d_ += __shfl_xor(d_, 32);
        den[it] = d_;
    }
    float* outp = out + ((size_t)(b * Ndim + ibase)) * HDc + w * Dd + i;
    #pragma unroll
    for (int it = 0; it < 4; ++it) {
        #pragma unroll
        for (int reg = 0; reg < 4; ++reg) {
            int row = it * 16 + q * 4 + reg;
            float rd = 1.0f / __shfl(den[it], q * 4 + reg, 64);
            outp[(size_t)row * HDc]      = C[it][0][reg] * rd;
            outp[(size_t)row * HDc + 16] = C[it][1][reg] * rd;
        }
    }
}

extern "C" void kernel_launch(void* const* d_in, const int* in_sizes, int n_in,
                              void* d_out, int out_size, void* d_ws, size_t ws_size,
                              hipStream_t stream) {
    const float* x    = (const float*)d_in[0];
    const int*   adj  = (const int*)d_in[1];
    const float* W    = (const float*)d_in[2];
    const float* bias = (const float*)d_in[3];
    const float* a    = (const float*)d_in[4];
    float* out = (float*)d_out;

    // ws: pk 2MB | hTh 4MB | hTl 4MB | eiT 256K | ejT 256K | WTh/WTl 36K | bias2
    unsigned long long* pk64 = (unsigned long long*)d_ws;
    unsigned int* pk32 = (unsigned int*)d_ws;
    unsigned short* hTh = (unsigned short*)((char*)d_ws + 2 * 1024 * 1024);
    unsigned short* hTl = hTh + (size_t)Bdim * HDc * Ndim;
    float* eiT = (float*)(hTl + (size_t)Bdim * HDc * Ndim);
    float* ejT = eiT + (size_t)Bdim * Hh * Ndim;
    unsigned short* WTh = (unsigned short*)(ejT + (size_t)Bdim * Hh * Ndim);
    unsigned short* WTl = WTh + 144 * 128;
    float* bias2 = (float*)(WTl + 144 * 128);

    split_w_kernel<<<dim3(17), dim3(256), 0, stream>>>(W, bias, a, WTh, WTl, bias2);
    pack_kernel<<<dim3(2048), dim3(256), 0, stream>>>(adj, pk64);
    proj_kernel<<<dim3(256), dim3(256), 0, stream>>>(
        x, WTh, WTl, bias2, hTh, hTl, eiT, ejT);
    gat_kernel<<<dim3(256), dim3(256), 0, stream>>>(
        pk32, hTh, hTl, eiT, ejT, out);
}